// Round 8
// baseline (98.333 us; speedup 1.0000x reference)
//
#include <hip/hip_runtime.h>

// TopologyAwareAttention — ONE kernel. Sync law learned R2/R5/R6/R7:
// cost ~ (coherence-point accesses) x (same-line fan-in). So:
//  - producers->consumers hand off via plain stores + release fence + per-block
//    MAGIC flag on a DISTINCT 64B line (1 relaxed-atomic poller per block);
//  - consumers gather LUT/centers with PLAIN cached loads after ONE acquire;
//  - only the 2 stats blocks do atomic gathers (450 tagged words — proven cheap);
//  - consumers preload their attn tile into VGPRs BEFORE the wait.
// Math: f(t)=sum_e relu(t*w1[e]+b1[e])*mean_h(w2[e,:]) + mean(b2); centers on a
// 16x16 grid => d2=dx^2+dy^2 in [0,450] => 451-entry LUT; mean dist via cell
// histogram. Cost model: dur ~= 63us fixed + 7us/node + kernel.

#define NQ      900
#define LUT_N   451
#define TAG     0xC0DE0000u
#define MAGIC64 0xC0DEC0DE13572468ull

__device__ __forceinline__ int aload_rlx(const int* p) {
    return __hip_atomic_load(p, __ATOMIC_RELAXED, __HIP_MEMORY_SCOPE_AGENT);
}
__device__ __forceinline__ void astore_rlx(int* p, int v) {
    __hip_atomic_store(p, v, __ATOMIC_RELAXED, __HIP_MEMORY_SCOPE_AGENT);
}
__device__ __forceinline__ unsigned long long aload_rlx64(const unsigned long long* p) {
    return __hip_atomic_load(p, __ATOMIC_RELAXED, __HIP_MEMORY_SCOPE_AGENT);
}
__device__ __forceinline__ void astore_rlx64(unsigned long long* p, unsigned long long v) {
    __hip_atomic_store(p, v, __ATOMIC_RELAXED, __HIP_MEMORY_SCOPE_AGENT);
}

__global__ __launch_bounds__(256, 2)
void fused(const float* __restrict__ attn,
           const float* __restrict__ ref,
           const float* __restrict__ lam_p,
           const float* __restrict__ w1,
           const float* __restrict__ b1,
           const float* __restrict__ w2,
           const float* __restrict__ b2,
           float* __restrict__ out,
           int* __restrict__ ws) {
    // ws: cent2[900] tagged | pad to 4096B | flags (450 x 64B-strided u64)
    //     | lutp[2][451] plain | centp[2][225] plain packed u8x4
    int* cent2 = ws;
    unsigned long long* flags = (unsigned long long*)(ws + 1024);   // 28800 B
    float* lutp  = (float*)(ws + 1024 + 7200);
    int*   centp = ws + 1024 + 7200 + 2 * LUT_N;

    __shared__ int   cpk[225];              // packed centers, used by apply
    __shared__ float lut_s[LUT_N];
    __shared__ int   idx_s[NQ];             // stats blocks only
    __shared__ float sqs[LUT_N];            // stats blocks only
    __shared__ int   hsh[256];              // stats blocks only
    __shared__ float w1s[256], b1s[256], wbars[256];
    __shared__ float wsum[4];
    __shared__ int   ctmp[4];

    const int tid  = threadIdx.x;
    const int lane = tid & 63;
    const int wave = tid >> 6;
    const int blk  = blockIdx.x;
    const int b    = (blk >= 225) ? 1 : 0;  // batch
    const int i0   = (blk - b * 225) * 4;   // local row base
    const bool stats = (blk == 0 || blk == 225);

    // ---- P1: argmax, one wave per query (4 queries/block) ----
    {
        int q = blk * 4 + wave;             // global row 0..1799
        const float* p = ref + (size_t)q * 256;
        float bv = p[lane];
        int   bi = lane;
        #pragma unroll
        for (int k = 1; k < 4; ++k) {
            float v = p[lane + 64 * k];
            if (v > bv) { bv = v; bi = lane + 64 * k; }   // strict > = first max
        }
        #pragma unroll
        for (int off = 32; off >= 1; off >>= 1) {
            float ov = __shfl_down(bv, off, 64);
            int   oi = __shfl_down(bi, off, 64);
            if (ov > bv || (ov == bv && oi < bi)) { bv = ov; bi = oi; }
        }
        if (lane == 0) ctmp[wave] = bi;     // iy*16+ix, fits u8
    }
    if (stats) {                             // overlap: stage stats tables
        hsh[tid] = 0;
        w1s[tid] = w1[tid];
        b1s[tid] = b1[tid];
        float s8 = 0.f;
        #pragma unroll
        for (int h = 0; h < 8; ++h) s8 += w2[tid * 8 + h];
        wbars[tid] = s8 * 0.125f;
        for (int s = tid; s < LUT_N; s += 256) sqs[s] = sqrtf((float)s);
    }
    __syncthreads();
    if (tid == 0) {
        astore_rlx(&cent2[blk*2+0], (int)(TAG | ((ctmp[0]&255)<<8) | (ctmp[1]&255)));
        astore_rlx(&cent2[blk*2+1], (int)(TAG | ((ctmp[2]&255)<<8) | (ctmp[3]&255)));
    }

    // ---- preload attn tile into VGPRs (in flight across the wait) ----
    float4 pre0, pre1, pre2, pre3;
    if (tid < 225) {
        const float* ab = attn + (size_t)(b * NQ + i0) * NQ + tid * 4;
        pre0 = *(const float4*)(ab);
        pre1 = *(const float4*)(ab + NQ);
        pre2 = *(const float4*)(ab + 2 * NQ);
        pre3 = *(const float4*)(ab + 3 * NQ);
    }

    if (stats) {
        // ---- atomic gather of 450 tagged words (2 blocks only — cheap) ----
        for (int k = tid; k < 450; k += 256) {
            int w;
            while (((unsigned)(w = aload_rlx(&cent2[b*450 + k])) & 0xFFFF0000u) != TAG)
                __builtin_amdgcn_s_sleep(1);
            idx_s[2*k]     = (w >> 8) & 255;
            idx_s[2*k + 1] =  w       & 255;
        }
        __syncthreads();
        for (int k = tid; k < NQ; k += 256) atomicAdd(&hsh[idx_s[k]], 1);
        __syncthreads();
        // pair-sum via histogram; thread owns c2 = tid
        float local = 0.f;
        {
            int h2v = hsh[tid];
            if (h2v) {
                int ix2 = tid & 15, iy2 = tid >> 4;
                for (int c1 = 0; c1 < 256; ++c1) {
                    int h1 = hsh[c1];
                    int dx = (c1 & 15) - ix2;
                    int dy = (c1 >> 4) - iy2;
                    local += (float)h1 * sqs[dx*dx + dy*dy];
                }
                local *= (float)h2v;
            }
        }
        #pragma unroll
        for (int off = 32; off >= 1; off >>= 1) local += __shfl_down(local, off, 64);
        if (lane == 0) wsum[wave] = local;
        __syncthreads();
        float tot   = wsum[0] + wsum[1] + wsum[2] + wsum[3];
        float mean  = tot * (1.f/15.f) * (1.f/((float)NQ*(float)NQ));
        float inv   = 1.f / (mean + 1e-6f);
        float b2bar = 0.125f * (b2[0]+b2[1]+b2[2]+b2[3]+b2[4]+b2[5]+b2[6]+b2[7]);
        float lam   = lam_p[0];
        for (int s = tid; s < LUT_N; s += 256) {
            float t   = sqs[s] * (1.f/15.f) * inv;
            float acc = b2bar;
            for (int i = 0; i < 256; ++i) {
                float hv = fmaf(t, w1s[i], b1s[i]);
                acc = fmaf(fmaxf(hv, 0.f), wbars[i], acc);
            }
            float v = lam * acc;
            lut_s[s] = v;
            lutp[b * LUT_N + s] = v;            // plain store
        }
        if (tid < 225) {                        // pack centers u8x4
            int w = (idx_s[4*tid] & 255) | ((idx_s[4*tid+1] & 255) << 8) |
                    ((idx_s[4*tid+2] & 255) << 16) | ((idx_s[4*tid+3] & 255) << 24);
            cpk[tid] = w;
            centp[b * 225 + tid] = w;           // plain store
        }
        __syncthreads();                        // drains vmcnt before barrier
        if (tid < 225) {                        // release + per-consumer flag line
            __builtin_amdgcn_fence(__ATOMIC_RELEASE, "agent");
            astore_rlx64(&flags[(size_t)(b * 225 + tid) * 8], MAGIC64);
        }
    } else {
        // ---- consumer: poll OWN distinct flag line, then plain gather ----
        if (tid == 0) {
            while (aload_rlx64(&flags[(size_t)blk * 8]) != MAGIC64)
                __builtin_amdgcn_s_sleep(4);
        }
        __syncthreads();
        __builtin_amdgcn_fence(__ATOMIC_ACQUIRE, "agent");
        if (tid < 225) cpk[tid] = centp[b * 225 + tid];     // plain, L2-cached
        for (int s = tid; s < LUT_N; s += 256) lut_s[s] = lutp[b * LUT_N + s];
        __syncthreads();
    }

    // ---- P3: apply 4 rows x 225 float4 from preloaded registers ----
    if (tid < 225) {
        int cw  = cpk[tid];                     // packed centers of cols 4t..4t+3
        int cx0 = (cw      ) & 15, cy0 = ((cw >>  4) & 15);
        int cx1 = (cw >>  8) & 15, cy1 = ((cw >> 12) & 15);
        int cx2 = (cw >> 16) & 15, cy2 = ((cw >> 20) & 15);
        int cx3 = (cw >> 24) & 15, cy3 = ((cw >> 28) & 15);
        float4 va[4] = {pre0, pre1, pre2, pre3};
        #pragma unroll
        for (int lr = 0; lr < 4; ++lr) {
            int i  = i0 + lr;
            int ci = (cpk[i >> 2] >> ((i & 3) * 8)) & 255;
            int ixi = ci & 15, iyi = ci >> 4;
            float4 a = va[lr];
            int dx, dy;
            dx = ixi - cx0; dy = iyi - cy0; a.x += lut_s[dx*dx + dy*dy];
            dx = ixi - cx1; dy = iyi - cy1; a.y += lut_s[dx*dx + dy*dy];
            dx = ixi - cx2; dy = iyi - cy2; a.z += lut_s[dx*dx + dy*dy];
            dx = ixi - cx3; dy = iyi - cy3; a.w += lut_s[dx*dx + dy*dy];
            *(float4*)(out + (size_t)(b * NQ + i) * NQ + tid * 4) = a;
        }
    }
}

extern "C" void kernel_launch(void* const* d_in, const int* in_sizes, int n_in,
                              void* d_out, int out_size, void* d_ws, size_t ws_size,
                              hipStream_t stream) {
    const float* attn = (const float*)d_in[0];   // [2,900,900]
    const float* ref  = (const float*)d_in[1];   // [2,900,16,16]
    const float* lam  = (const float*)d_in[2];
    const float* w1   = (const float*)d_in[3];   // [256]
    const float* b1   = (const float*)d_in[4];   // [256]
    const float* w2   = (const float*)d_in[5];   // [256,8]
    const float* b2   = (const float*)d_in[6];   // [8]
    float* out = (float*)d_out;
    int*   ws  = (int*)d_ws;

    fused<<<450, 256, 0, stream>>>(attn, ref, lam, w1, b1, w2, b2, out, ws);
}

// Round 9
// 84.743 us; speedup vs baseline: 1.1604x; 1.1604x over previous
//
#include <hip/hip_runtime.h>

// TopologyAwareAttention — 2 kernels (R7 skeleton; kernel boundary is the only
// cheap device-wide sync: in-kernel handoffs cost ~20+us regardless of
// mechanism, measured R2/R5/R6/R8; a node costs ~7us).
//  f(t) = sum_e relu(t*w1[e]+b1[e]) * mean_h(w2[e,h]) + mean(b2)
//  centers on 16x16 grid => d2 = dx^2+dy^2 in [0,450] => 451-entry LUT/batch
//  mean dist via cell histogram: sum = SUM_{c1,c2} h[c1] h[c2] sqrt(d2)
// R9 micro-opts: K2 does 4 float4/thread (more MLP: outstanding loads, m13
// pattern) + packed centers; K1 splits LUT across 2 stats blocks per batch
// (one inner-loop pass per thread). Tagged words: high16=0xC0DE, 0xAA poison
// can't match => relaxed polls only, validity rides with data.

#define NQ    900
#define LUT_N 451
#define TAG   0xC0DE0000u

__device__ __forceinline__ int aload_rlx(const int* p) {
    return __hip_atomic_load(p, __ATOMIC_RELAXED, __HIP_MEMORY_SCOPE_AGENT);
}
__device__ __forceinline__ void astore_rlx(int* p, int v) {
    __hip_atomic_store(p, v, __ATOMIC_RELAXED, __HIP_MEMORY_SCOPE_AGENT);
}

// ws layout (ints): cent2[900] tagged | lutp[2*451] | centp[2*225]
__global__ __launch_bounds__(256)
void k1_centers_stats(const float* __restrict__ ref,
                      const float* __restrict__ lam_p,
                      const float* __restrict__ w1,
                      const float* __restrict__ b1,
                      const float* __restrict__ w2,
                      const float* __restrict__ b2,
                      int* __restrict__ ws) {
    int*   cent2 = ws;
    float* lutp  = (float*)(ws + 900);
    int*   centp = ws + 900 + 2 * LUT_N;

    const int tid  = threadIdx.x;
    const int lane = tid & 63;
    const int wave = tid >> 6;
    const int blk  = blockIdx.x;

    if (blk < 450) {
        // ---- argmax: one wave per query, 4 queries per block ----
        __shared__ int ctmp[4];
        int q = blk * 4 + wave;                 // 0..1799
        const float* p = ref + (size_t)q * 256;
        float bv = p[lane];
        int   bi = lane;
        #pragma unroll
        for (int k = 1; k < 4; ++k) {
            float v = p[lane + 64 * k];
            if (v > bv) { bv = v; bi = lane + 64 * k; }   // strict > = first max
        }
        #pragma unroll
        for (int off = 32; off >= 1; off >>= 1) {
            float ov = __shfl_down(bv, off, 64);
            int   oi = __shfl_down(bi, off, 64);
            if (ov > bv || (ov == bv && oi < bi)) { bv = ov; bi = oi; }
        }
        if (lane == 0) ctmp[wave] = bi;         // iy*16+ix, fits u8
        __syncthreads();
        if (tid == 0) {
            // word blk*2 == b*450 + local_word (blocks 225.. are batch 1)
            astore_rlx(&cent2[blk*2+0], (int)(TAG | ((ctmp[0]&255)<<8) | (ctmp[1]&255)));
            astore_rlx(&cent2[blk*2+1], (int)(TAG | ((ctmp[2]&255)<<8) | (ctmp[3]&255)));
        }
        return;
    }

    // ---- stats: blocks 450..453 = (batch 0 half 0/1, batch 1 half 0/1) ----
    const int sb   = blk - 450;
    const int b    = sb >> 1;
    const int half = sb & 1;

    __shared__ int   idx_s[NQ];
    __shared__ float sqs[LUT_N];
    __shared__ int   hsh[256];
    __shared__ float w1s[256], b1s[256], wbars[256];
    __shared__ float wsum[4];

    hsh[tid] = 0;
    w1s[tid] = w1[tid];
    b1s[tid] = b1[tid];
    {
        float s8 = 0.f;
        #pragma unroll
        for (int h = 0; h < 8; ++h) s8 += w2[tid * 8 + h];
        wbars[tid] = s8 * 0.125f;
    }
    for (int s = tid; s < LUT_N; s += 256) sqs[s] = sqrtf((float)s);

    for (int k = tid; k < 450; k += 256) {      // <=2 distinct words per thread
        int w;
        while (((unsigned)(w = aload_rlx(&cent2[b * 450 + k])) & 0xFFFF0000u) != TAG)
            __builtin_amdgcn_s_sleep(1);
        idx_s[2 * k]     = (w >> 8) & 255;
        idx_s[2 * k + 1] =  w       & 255;
    }
    __syncthreads();

    for (int k = tid; k < NQ; k += 256) atomicAdd(&hsh[idx_s[k]], 1);
    __syncthreads();

    float local = 0.f;
    {
        int h2v = hsh[tid];                     // thread owns c2 = tid
        if (h2v) {
            int ix2 = tid & 15, iy2 = tid >> 4;
            for (int c1 = 0; c1 < 256; ++c1) {
                int h1 = hsh[c1];               // broadcast read
                int dx = (c1 & 15) - ix2;
                int dy = (c1 >> 4) - iy2;
                local += (float)h1 * sqs[dx * dx + dy * dy];
            }
            local *= (float)h2v;
        }
    }
    #pragma unroll
    for (int off = 32; off >= 1; off >>= 1) local += __shfl_down(local, off, 64);
    if (lane == 0) wsum[wave] = local;
    __syncthreads();

    float tot   = wsum[0] + wsum[1] + wsum[2] + wsum[3];
    float mean  = tot * (1.f / 15.f) * (1.f / ((float)NQ * (float)NQ));
    float inv   = 1.f / (mean + 1e-6f);
    float b2bar = 0.125f * (b2[0] + b2[1] + b2[2] + b2[3] +
                            b2[4] + b2[5] + b2[6] + b2[7]);
    float lam   = lam_p[0];

    // my half of the LUT: one pass per thread (226 or 225 entries <= 256)
    {
        int s0  = half * 226;
        int cnt = half ? 225 : 226;
        if (tid < cnt) {
            int   s   = s0 + tid;
            float t   = sqs[s] * (1.f / 15.f) * inv;
            float acc = b2bar;
            for (int i = 0; i < 256; ++i) {
                float hv = fmaf(t, w1s[i], b1s[i]);
                acc = fmaf(fmaxf(hv, 0.f), wbars[i], acc);
            }
            lutp[b * LUT_N + s] = lam * acc;    // plain store; boundary syncs
        }
    }
    if (half == 0 && tid < 225) {               // pack centers u8x4 once
        centp[b * 225 + tid] = (idx_s[4*tid] & 255) |
                               ((idx_s[4*tid+1] & 255) << 8) |
                               ((idx_s[4*tid+2] & 255) << 16) |
                               ((idx_s[4*tid+3] & 255) << 24);
    }
}

__global__ __launch_bounds__(256)
void k2_apply(const float* __restrict__ attn,
              const int* __restrict__ ws,
              float* __restrict__ out) {
    const float* lutp  = (const float*)(ws + 900);
    const int*   centp = ws + 900 + 2 * LUT_N;
    const int b = blockIdx.y;

    __shared__ float lut_s[LUT_N];
    __shared__ int   cpk[225];                  // packed centers (word t: q 4t..4t+3)
    if (threadIdx.x < 225) cpk[threadIdx.x] = centp[b * 225 + threadIdx.x];
    for (int s = threadIdx.x; s < LUT_N; s += 256) lut_s[s] = lutp[b * LUT_N + s];
    __syncthreads();

    // 4 float4 per thread, 1024 f4 per block, 198 blocks per batch
    const int base_f4 = blockIdx.x * 1024 + threadIdx.x;
    #pragma unroll
    for (int u = 0; u < 4; ++u) {
        int f4 = base_f4 + u * 256;
        if (f4 < 202500) {
            int i  = f4 / 225;                  // row
            int j4 = f4 - i * 225;              // float4 within row (cols 4j4..)
            int ci = (cpk[i >> 2] >> ((i & 3) * 8)) & 255;   // mostly broadcast
            int ixi = ci & 15, iyi = ci >> 4;
            int cw = cpk[j4];                   // stride-1, conflict-free
            size_t g = (size_t)b * (NQ * NQ) + (size_t)i * NQ + j4 * 4;
            float4 a = *(const float4*)(attn + g);
            int c, dx, dy;
            c = cw & 255;         dx = ixi - (c & 15); dy = iyi - (c >> 4); a.x += lut_s[dx*dx + dy*dy];
            c = (cw >> 8) & 255;  dx = ixi - (c & 15); dy = iyi - (c >> 4); a.y += lut_s[dx*dx + dy*dy];
            c = (cw >> 16) & 255; dx = ixi - (c & 15); dy = iyi - (c >> 4); a.z += lut_s[dx*dx + dy*dy];
            c = (cw >> 24) & 255; dx = ixi - (c & 15); dy = iyi - (c >> 4); a.w += lut_s[dx*dx + dy*dy];
            *(float4*)(out + g) = a;
        }
    }
}

extern "C" void kernel_launch(void* const* d_in, const int* in_sizes, int n_in,
                              void* d_out, int out_size, void* d_ws, size_t ws_size,
                              hipStream_t stream) {
    const float* attn = (const float*)d_in[0];   // [2,900,900]
    const float* ref  = (const float*)d_in[1];   // [2,900,16,16]
    const float* lam  = (const float*)d_in[2];
    const float* w1   = (const float*)d_in[3];   // [256]
    const float* b1   = (const float*)d_in[4];   // [256]
    const float* w2   = (const float*)d_in[5];   // [256,8]
    const float* b2   = (const float*)d_in[6];   // [8]
    float* out = (float*)d_out;
    int*   ws  = (int*)d_ws;                     // cent2[900]|lutp[902]|centp[450]

    k1_centers_stats<<<454, 256, 0, stream>>>(ref, lam, w1, b1, w2, b2, ws);
    k2_apply<<<dim3(198, 2), 256, 0, stream>>>(attn, ws, out);
}